// Round 5
// baseline (2163.489 us; speedup 1.0000x reference)
//
#include <hip/hip_runtime.h>

// RGCN, 3 layers. N=100000, E=1.6M, R=16, HID=64.
// Edges counting-sorted by (dst,rel), metadata packed to one u32/edge.
// Per layer (8 nodes/block, 4 blocks/CU): phase 1 = 4-edges-per-instruction
// gathers (lane l: edge l>>4, dims (l&15)*4, 8B dwordx2) -> 32 edges in
// flight per wave -> ds_add_f32 into fp32 LDS H[8][1024]; phase 2 = K-split
// MFMA ([H|x] @ Wcat, K=1088) + cross-wave reduction in LDS.

#define HID   64
#define NREL  16
#define KD    1088          // NREL*HID + HID (root x appended as extra K)
#define NPB   8             // nodes per block
#define HSTR  1028          // fp32 LDS row stride (16B-aligned)
#define PSTR  65            // partial-C row stride (floats)
#define PW    (NPB * PSTR)  // per-wave partial-C size

typedef __attribute__((ext_vector_type(8))) short bf16x8;
typedef __attribute__((ext_vector_type(4))) float f32x4;
typedef unsigned short us16;
typedef unsigned int u32;

__device__ __forceinline__ float b2f(us16 u) {
    union { u32 i; float f; } c; c.i = ((u32)u) << 16; return c.f;
}
__device__ __forceinline__ us16 f2b(float f) {   // round-to-nearest-even
    union { float f; u32 i; } c; c.f = f;
    u32 x = c.i;
    return (us16)((x + 0x7FFFu + ((x >> 16) & 1u)) >> 16);
}
__device__ __forceinline__ u32 pack2(float lo, float hi) {  // 2xf32 -> bf16x2
    u32 a = __float_as_uint(lo) + 0x8000u;
    u32 b = __float_as_uint(hi) + 0x8000u;
    return (a >> 16) | (b & 0xFFFF0000u);
}

// ---------- setup: counting sort by (dst*16+rel) ----------

__global__ void count_kernel(const int* __restrict__ ei, const int* __restrict__ et,
                             int* __restrict__ counts16, int E) {
    int e = blockIdx.x * 256 + threadIdx.x;
    if (e < E) {
        int dst = ei[E + e];
        int t   = et[e];
        atomicAdd(&counts16[dst * NREL + t], 1);
    }
}

__global__ __launch_bounds__(1024) void scan1(const int* __restrict__ counts16,
                                              int* __restrict__ seg,
                                              int* __restrict__ sums, int nr16) {
    __shared__ int s[1024];
    int t = threadIdx.x;
    int g4 = (blockIdx.x * 1024 + t) * 4;
    int c0 = 0, c1 = 0, c2 = 0, c3 = 0;
    if (g4 + 3 < nr16) {
        const int4 v = *(const int4*)(counts16 + g4);
        c0 = v.x; c1 = v.y; c2 = v.z; c3 = v.w;
    } else {
        if (g4 + 0 < nr16) c0 = counts16[g4 + 0];
        if (g4 + 1 < nr16) c1 = counts16[g4 + 1];
        if (g4 + 2 < nr16) c2 = counts16[g4 + 2];
        if (g4 + 3 < nr16) c3 = counts16[g4 + 3];
    }
    int loc = c0 + c1 + c2 + c3;
    s[t] = loc; __syncthreads();
    for (int off = 1; off < 1024; off <<= 1) {
        int tv = (t >= off) ? s[t - off] : 0;
        __syncthreads();
        s[t] += tv;
        __syncthreads();
    }
    int ex = s[t] - loc;
    if (g4 + 0 < nr16) seg[g4 + 0] = ex;
    if (g4 + 1 < nr16) seg[g4 + 1] = ex + c0;
    if (g4 + 2 < nr16) seg[g4 + 2] = ex + c0 + c1;
    if (g4 + 3 < nr16) seg[g4 + 3] = ex + c0 + c1 + c2;
    if (t == 1023) sums[blockIdx.x] = s[1023];
}

__global__ void scan2(int* __restrict__ sums, int nb,
                      int* __restrict__ row_ptr, int N, int E) {  // 1 block, 512 thr
    __shared__ int s[512];
    int t = threadIdx.x;
    int v = (t < nb) ? sums[t] : 0;
    s[t] = v; __syncthreads();
    for (int off = 1; off < 512; off <<= 1) {
        int tv = (t >= off) ? s[t - off] : 0;
        __syncthreads();
        s[t] += tv;
        __syncthreads();
    }
    if (t < nb) sums[t] = s[t] - v;
    if (t == 0) row_ptr[N] = E;
}

__global__ __launch_bounds__(1024) void scan3(int* __restrict__ seg,
                                              const int* __restrict__ sums,
                                              int* __restrict__ row_ptr, int nr16) {
    int t = threadIdx.x;
    int g4 = (blockIdx.x * 1024 + t) * 4;
    int add = sums[blockIdx.x];
    #pragma unroll
    for (int j = 0; j < 4; ++j) {
        int g = g4 + j;
        if (g < nr16) {
            int v = seg[g] + add;
            seg[g] = v;                          // becomes cursor
            if ((g & 15) == 0) row_ptr[g >> 4] = v;
        }
    }
}

// md[pos] = src | rel<<17 | (dst % NPB)<<21 | min(count,127)<<25
__global__ void place_kernel(const int* __restrict__ ei, const int* __restrict__ et,
                             const int* __restrict__ counts16,
                             int* __restrict__ cursor16,
                             u32* __restrict__ md, int E) {
    int e = blockIdx.x * 256 + threadIdx.x;
    if (e < E) {
        int src = ei[e], dst = ei[E + e], t = et[e];
        int sidx = dst * NREL + t;
        int pos = atomicAdd(&cursor16[sidx], 1);
        int cnt = counts16[sidx]; if (cnt > 127) cnt = 127;
        md[pos] = (u32)src | ((u32)t << 17) | ((u32)(dst & (NPB - 1)) << 21) | ((u32)cnt << 25);
    }
}

__global__ void convx_kernel(const float* __restrict__ x, us16* __restrict__ xb, int n4) {
    int i = blockIdx.x * 256 + threadIdx.x;    // n4 = N*HID/4
    if (i < n4) {
        float4 v = ((const float4*)x)[i];
        us16* o = xb + i * 4;
        o[0] = f2b(v.x); o[1] = f2b(v.y); o[2] = f2b(v.z); o[3] = f2b(v.w);
    }
}

// WcatT[l][h][k], k = r*64+d for k<1024, else root d = k-1024.  bf16.
__global__ void convw_kernel(const float* __restrict__ W, const float* __restrict__ Wroot,
                             us16* __restrict__ WcatT, int total, int L) {
    int i = blockIdx.x * 256 + threadIdx.x;    // total = L*HID*KD
    if (i < total) {
        int l = i / (HID * KD);
        int rem = i % (HID * KD);
        int h = rem / KD, k = rem % KD;
        float v;
        if (k < NREL * HID) {
            int r = k >> 6, d = k & 63;
            v = W[(((size_t)l * NREL + r) * HID + d) * HID + h];
        } else {
            int d = k - NREL * HID;
            v = Wroot[((size_t)l * HID + d) * HID + h];
        }
        WcatT[i] = f2b(v);
    }
}

// ---------- fused layer kernel ----------

__global__ __launch_bounds__(256, 4) void layer_kernel(
        const us16* __restrict__ x_in,        // bf16 [N,64]
        const int*  __restrict__ row_ptr,     // [N+1]
        const u32*  __restrict__ md,          // sorted packed edge metadata
        const us16* __restrict__ WcatT,       // bf16 [64][1088] this layer
        const float* __restrict__ bias,       // fp32 [64] this layer
        us16* __restrict__ x_out,             // bf16 [N,64]  (if !last)
        float* __restrict__ out_f32,          // fp32 [N,64]  (if last)
        int flags, int N)                     // flags: 1=relu, 2=last
{
    __shared__ __align__(16) float Hf[NPB * HSTR];     // 32896 B -> 4 blocks/CU
    const int tid = threadIdx.x, wave = tid >> 6, lane = tid & 63;
    const int node0 = blockIdx.x * NPB;

    // zero H
    float4 z4 = {0.f, 0.f, 0.f, 0.f};
    float4* Hz = (float4*)Hf;
    for (int i = tid; i < NPB * HSTR / 4; i += 256) Hz[i] = z4;
    __syncthreads();

    // ---- phase 1: 4 edges per gather instruction, 32 edges in flight ----
    int es = row_ptr[node0];
    int ee = row_ptr[min(node0 + NPB, N)];
    const int g16 = lane >> 4;          // edge-within-quad
    const int d4  = (lane & 15) * 4;    // dim start for this lane

    for (int base = es + wave * 32; base < ee; base += 128) {
        // coalesced metadata load for this wave's 32 edges
        u32 p_l = md[min(base + (lane & 31), ee - 1)];
        u32 pg[8]; u32 gx[8], gy[8];
        #pragma unroll
        for (int i = 0; i < 8; ++i) {
            pg[i] = (u32)__shfl((int)p_l, i * 4 + g16);
            int src = (int)(pg[i] & 0x1FFFFu);
            const u32* gp = (const u32*)(x_in + src * HID + d4);
            gx[i] = gp[0]; gy[i] = gp[1];        // 8B dwordx2, 4 edges/instr
        }
        #pragma unroll
        for (int i = 0; i < 8; ++i) {
            int e = base + i * 4 + g16;
            bool valid = e < ee;
            float w = valid ? __builtin_amdgcn_rcpf((float)(pg[i] >> 25)) : 0.f;
            int off = (int)((pg[i] >> 21) & (NPB - 1)) * HSTR
                    + (int)((pg[i] >> 17) & 15u) * HID + d4;
            float f0 = __uint_as_float(gx[i] << 16);
            float f1 = __uint_as_float(gx[i] & 0xFFFF0000u);
            float f2 = __uint_as_float(gy[i] << 16);
            float f3 = __uint_as_float(gy[i] & 0xFFFF0000u);
            atomicAdd(&Hf[off + 0], w * f0);
            atomicAdd(&Hf[off + 1], w * f1);
            atomicAdd(&Hf[off + 2], w * f2);
            atomicAdd(&Hf[off + 3], w * f3);
        }
    }
    __syncthreads();

    // ---- phase 2: K-split MFMA. wave w: ks = w, w+4, ... ; all 64 cols ----
    const int n16 = lane & 15, quad = lane >> 4;
    const int arow = n16 & (NPB - 1);              // A rows 8-15 duplicate 0-7
    f32x4 acc0 = {0.f,0.f,0.f,0.f}, acc1 = {0.f,0.f,0.f,0.f};
    f32x4 acc2 = {0.f,0.f,0.f,0.f}, acc3 = {0.f,0.f,0.f,0.f};

    #pragma unroll 2
    for (int ks = wave; ks < 34; ks += 4) {
        bf16x8 af;
        if (ks < 32) {
            const float* Ap = Hf + arow * HSTR + ks * 32 + quad * 8;
            float4 a0 = *(const float4*)Ap;
            float4 a1 = *(const float4*)(Ap + 4);
            u32 aw[4];
            aw[0] = pack2(a0.x, a0.y); aw[1] = pack2(a0.z, a0.w);
            aw[2] = pack2(a1.x, a1.y); aw[3] = pack2(a1.z, a1.w);
            af = *(bf16x8*)aw;
        } else {                                   // root x K-tail from global
            int nrow = min(node0 + arow, N - 1);
            af = *(const bf16x8*)(x_in + (size_t)nrow * HID + (ks - 32) * 32 + quad * 8);
        }
        const us16* Bk = WcatT + (size_t)n16 * KD + ks * 32 + quad * 8;
        bf16x8 b0 = *(const bf16x8*)(Bk);
        bf16x8 b1 = *(const bf16x8*)(Bk + (size_t)16 * KD);
        bf16x8 b2 = *(const bf16x8*)(Bk + (size_t)32 * KD);
        bf16x8 b3 = *(const bf16x8*)(Bk + (size_t)48 * KD);
        acc0 = __builtin_amdgcn_mfma_f32_16x16x32_bf16(af, b0, acc0, 0, 0, 0);
        acc1 = __builtin_amdgcn_mfma_f32_16x16x32_bf16(af, b1, acc1, 0, 0, 0);
        acc2 = __builtin_amdgcn_mfma_f32_16x16x32_bf16(af, b2, acc2, 0, 0, 0);
        acc3 = __builtin_amdgcn_mfma_f32_16x16x32_bf16(af, b3, acc3, 0, 0, 0);
    }
    __syncthreads();                               // all H reads done

    // ---- cross-wave reduction (reuse Hf as 4 partial-C buffers) ----
    float* Pf = Hf;
    #pragma unroll
    for (int ri = 0; ri < 4; ++ri) {               // C/D: col=lane&15, row=quad*4+reg
        int row = quad * 4 + ri;
        if (row < NPB) {
            Pf[wave * PW + row * PSTR +  0 + n16] = acc0[ri];
            Pf[wave * PW + row * PSTR + 16 + n16] = acc1[ri];
            Pf[wave * PW + row * PSTR + 32 + n16] = acc2[ri];
            Pf[wave * PW + row * PSTR + 48 + n16] = acc3[ri];
        }
    }
    __syncthreads();

    #pragma unroll
    for (int pass = 0; pass < 2; ++pass) {
        int nl = wave * 2 + pass;                  // 0..7
        int node = node0 + nl;
        float v = Pf[0 * PW + nl * PSTR + lane] + Pf[1 * PW + nl * PSTR + lane]
                + Pf[2 * PW + nl * PSTR + lane] + Pf[3 * PW + nl * PSTR + lane];
        v += bias[lane];
        if (flags & 1) v = fmaxf(v, 0.f);
        if (node < N) {
            if (flags & 2) out_f32[(size_t)node * HID + lane] = v;
            else           x_out [(size_t)node * HID + lane] = f2b(v);
        }
    }
}

// ---------- host ----------

extern "C" void kernel_launch(void* const* d_in, const int* in_sizes, int n_in,
                              void* d_out, int out_size, void* d_ws, size_t ws_size,
                              hipStream_t stream) {
    const int*   edge_index = (const int*)  d_in[0];
    const int*   edge_type  = (const int*)  d_in[1];
    const float* node_emb   = (const float*)d_in[2];
    const float* W          = (const float*)d_in[3];
    const float* Wroot      = (const float*)d_in[4];
    const float* bias       = (const float*)d_in[5];
    float* out = (float*)d_out;

    const int E = in_sizes[1];
    const int N = in_sizes[2] / HID;
    const int L = in_sizes[5] / HID;
    const int NR16 = N * NREL;

    char* p = (char*)d_ws;
    size_t off = 0;
    auto carve = [&](size_t bytes) {
        void* q = p + off;
        off = (off + bytes + 255) & ~(size_t)255;
        return q;
    };
    int*   counts16 = (int*)  carve((size_t)NR16 * 4);
    int*   segcur   = (int*)  carve((size_t)NR16 * 4);
    int*   row_ptr  = (int*)  carve((size_t)(N + 1) * 4);
    int*   sums     = (int*)  carve(512 * 4);
    u32*   md       = (u32*)  carve((size_t)E * 4);
    us16*  xb0      = (us16*) carve((size_t)N * HID * 2);
    us16*  xb1      = (us16*) carve((size_t)N * HID * 2);
    us16*  WcatT    = (us16*) carve((size_t)L * HID * KD * 2);
    (void)ws_size; (void)n_in; (void)out_size;

    hipMemsetAsync(counts16, 0, (size_t)NR16 * 4, stream);

    int ge  = (E + 255) / 256;
    int nb4 = (NR16 + 4095) / 4096;
    count_kernel<<<ge, 256, 0, stream>>>(edge_index, edge_type, counts16, E);
    scan1<<<nb4, 1024, 0, stream>>>(counts16, segcur, sums, NR16);
    scan2<<<1, 512, 0, stream>>>(sums, nb4, row_ptr, N, E);
    scan3<<<nb4, 1024, 0, stream>>>(segcur, sums, row_ptr, NR16);
    place_kernel<<<ge, 256, 0, stream>>>(edge_index, edge_type, counts16, segcur, md, E);
    convx_kernel<<<(N * HID / 4 + 255) / 256, 256, 0, stream>>>(node_emb, xb0, N * HID / 4);
    int wtot = L * HID * KD;
    convw_kernel<<<(wtot + 255) / 256, 256, 0, stream>>>(W, Wroot, WcatT, wtot, L);

    int gl = (N + NPB - 1) / NPB;
    us16* xin = xb0;
    us16* xother = xb1;
    for (int l = 0; l < L; ++l) {
        int last = (l == L - 1);
        int flags = (last ? 2 : 1);
        layer_kernel<<<gl, 256, 0, stream>>>(
            xin, row_ptr, md,
            WcatT + (size_t)l * HID * KD, bias + (size_t)l * HID,
            last ? nullptr : xother, last ? out : nullptr,
            flags, N);
        us16* t = xin; xin = xother; xother = t;
    }
}

// Round 6
// 806.190 us; speedup vs baseline: 2.6836x; 2.6836x over previous
//
#include <hip/hip_runtime.h>

// RGCN, 3 layers. N=100000, E=1.6M, R=16, HID=64.
// Edges counting-sorted by (dst,rel); md = src | rel<<20 (one u32/edge).
// Per layer (16 nodes/block, 4 waves, 4 nodes/wave): phase 1 aggregates
// per-(node,rel) means via run-length fp32 register accumulation (edges of a
// segment are contiguous), bf16 flush to LDS H[16][1088]; metadata windows
// and root-x rows for all 4 nodes prefetched up front, gathers batched 16
// deep for MLP. Phase 2: out = [H|x] @ Wcat via mfma_f32_16x16x32_bf16.

#define HID   64
#define NREL  16
#define KD    1088          // NREL*HID + HID (root x appended as extra K)
#define NPB   16            // nodes per block (= MFMA M)
#define LSTR  1096          // LDS row stride (pad 1088 -> 1096)

typedef __attribute__((ext_vector_type(8))) short bf16x8;
typedef __attribute__((ext_vector_type(4))) float f32x4;
typedef unsigned short us16;
typedef unsigned int u32;

__device__ __forceinline__ float b2f(us16 u) {
    union { u32 i; float f; } c; c.i = ((u32)u) << 16; return c.f;
}
__device__ __forceinline__ us16 f2b(float f) {   // round-to-nearest-even
    union { float f; u32 i; } c; c.f = f;
    u32 x = c.i;
    return (us16)((x + 0x7FFFu + ((x >> 16) & 1u)) >> 16);
}

// ---------- setup: counting sort by (dst*16+rel) ----------

__global__ void count_kernel(const int* __restrict__ ei, const int* __restrict__ et,
                             int* __restrict__ counts16, int E) {
    int e = blockIdx.x * 256 + threadIdx.x;
    if (e < E) {
        int dst = ei[E + e];
        int t   = et[e];
        atomicAdd(&counts16[dst * NREL + t], 1);
    }
}

__global__ __launch_bounds__(1024) void scan1(const int* __restrict__ counts16,
                                              int* __restrict__ seg,
                                              int* __restrict__ sums, int nr16) {
    __shared__ int s[1024];
    int t = threadIdx.x;
    int g4 = (blockIdx.x * 1024 + t) * 4;
    int c0 = 0, c1 = 0, c2 = 0, c3 = 0;
    if (g4 + 3 < nr16) {
        const int4 v = *(const int4*)(counts16 + g4);
        c0 = v.x; c1 = v.y; c2 = v.z; c3 = v.w;
    } else {
        if (g4 + 0 < nr16) c0 = counts16[g4 + 0];
        if (g4 + 1 < nr16) c1 = counts16[g4 + 1];
        if (g4 + 2 < nr16) c2 = counts16[g4 + 2];
        if (g4 + 3 < nr16) c3 = counts16[g4 + 3];
    }
    int loc = c0 + c1 + c2 + c3;
    s[t] = loc; __syncthreads();
    for (int off = 1; off < 1024; off <<= 1) {
        int tv = (t >= off) ? s[t - off] : 0;
        __syncthreads();
        s[t] += tv;
        __syncthreads();
    }
    int ex = s[t] - loc;
    if (g4 + 0 < nr16) seg[g4 + 0] = ex;
    if (g4 + 1 < nr16) seg[g4 + 1] = ex + c0;
    if (g4 + 2 < nr16) seg[g4 + 2] = ex + c0 + c1;
    if (g4 + 3 < nr16) seg[g4 + 3] = ex + c0 + c1 + c2;
    if (t == 1023) sums[blockIdx.x] = s[1023];
}

__global__ void scan2(int* __restrict__ sums, int nb,
                      int* __restrict__ row_ptr, int N, int E) {  // 1 block, 512 thr
    __shared__ int s[512];
    int t = threadIdx.x;
    int v = (t < nb) ? sums[t] : 0;
    s[t] = v; __syncthreads();
    for (int off = 1; off < 512; off <<= 1) {
        int tv = (t >= off) ? s[t - off] : 0;
        __syncthreads();
        s[t] += tv;
        __syncthreads();
    }
    if (t < nb) sums[t] = s[t] - v;
    if (t == 0) row_ptr[N] = E;
}

__global__ __launch_bounds__(1024) void scan3(int* __restrict__ seg,
                                              const int* __restrict__ sums,
                                              int* __restrict__ row_ptr, int nr16) {
    int t = threadIdx.x;
    int g4 = (blockIdx.x * 1024 + t) * 4;
    int add = sums[blockIdx.x];
    #pragma unroll
    for (int j = 0; j < 4; ++j) {
        int g = g4 + j;
        if (g < nr16) {
            int v = seg[g] + add;
            seg[g] = v;                          // becomes cursor
            if ((g & 15) == 0) row_ptr[g >> 4] = v;
        }
    }
}

// md[pos] = src | rel<<20
__global__ void place_kernel(const int* __restrict__ ei, const int* __restrict__ et,
                             int* __restrict__ cursor16,
                             u32* __restrict__ md, int E) {
    int e = blockIdx.x * 256 + threadIdx.x;
    if (e < E) {
        int src = ei[e], dst = ei[E + e], t = et[e];
        int pos = atomicAdd(&cursor16[dst * NREL + t], 1);
        md[pos] = (u32)src | ((u32)t << 20);
    }
}

__global__ void convx_kernel(const float* __restrict__ x, us16* __restrict__ xb, int n4) {
    int i = blockIdx.x * 256 + threadIdx.x;    // n4 = N*HID/4
    if (i < n4) {
        float4 v = ((const float4*)x)[i];
        us16* o = xb + i * 4;
        o[0] = f2b(v.x); o[1] = f2b(v.y); o[2] = f2b(v.z); o[3] = f2b(v.w);
    }
}

// WcatT[l][h][k], k = r*64+d for k<1024, else root d = k-1024.  bf16.
__global__ void convw_kernel(const float* __restrict__ W, const float* __restrict__ Wroot,
                             us16* __restrict__ WcatT, int total, int L) {
    int i = blockIdx.x * 256 + threadIdx.x;    // total = L*HID*KD
    if (i < total) {
        int l = i / (HID * KD);
        int rem = i % (HID * KD);
        int h = rem / KD, k = rem % KD;
        float v;
        if (k < NREL * HID) {
            int r = k >> 6, d = k & 63;
            v = W[(((size_t)l * NREL + r) * HID + d) * HID + h];
        } else {
            int d = k - NREL * HID;
            v = Wroot[((size_t)l * HID + d) * HID + h];
        }
        WcatT[i] = f2b(v);
    }
}

// ---------- fused layer kernel ----------

// process one 64-edge metadata window held in register p_l
__device__ __forceinline__ void proc_window(
        u32 p_l, int wcnt, const us16* __restrict__ x_in, us16* Hrow, int lane,
        float& acc, int& runlen, int& prev, u32& mask)
{
    #pragma unroll 1
    for (int c = 0; c < wcnt; c += 16) {
        us16 hv[16]; int rr[16];
        #pragma unroll
        for (int j = 0; j < 16; ++j) {           // 16 independent gathers in flight
            int idx = c + j; if (idx >= wcnt) idx = wcnt - 1;
            int pe = __shfl((int)p_l, idx);
            rr[j] = ((u32)pe) >> 20;
            hv[j] = x_in[(pe & 0xFFFFF) * HID + lane];
        }
        int m = wcnt - c; if (m > 16) m = 16;
        #pragma unroll
        for (int j = 0; j < 16; ++j) {
            if (j < m) {
                int r = rr[j];
                if (r != prev) {
                    if (prev >= 0) {
                        Hrow[(prev << 6) + lane] =
                            f2b(acc * __builtin_amdgcn_rcpf((float)runlen));
                        mask |= 1u << prev;
                    }
                    prev = r; acc = 0.f; runlen = 0;
                }
                acc += b2f(hv[j]); ++runlen;
            }
        }
    }
}

__global__ __launch_bounds__(256, 4) void layer_kernel(
        const us16* __restrict__ x_in,        // bf16 [N,64]
        const int*  __restrict__ row_ptr,     // [N+1]
        const u32*  __restrict__ md,          // sorted by (dst,rel): src | rel<<20
        const us16* __restrict__ WcatT,       // bf16 [64][1088] this layer
        const float* __restrict__ bias,       // fp32 [64] this layer
        us16* __restrict__ x_out,             // bf16 [N,64]  (if !last)
        float* __restrict__ out_f32,          // fp32 [N,64]  (if last)
        int flags, int N)                     // flags: 1=relu, 2=last
{
    __shared__ us16 H[NPB * LSTR];            // 35072 B -> 4 blocks/CU
    const int tid = threadIdx.x, wave = tid >> 6, lane = tid & 63;
    const int node0 = blockIdx.x * NPB;
    const int nodeq = node0 + wave * 4;

    // ---- phase 1 prologue: prefetch 4 nodes' metadata windows + root-x rows ----
    int rp[5];
    #pragma unroll
    for (int i = 0; i < 5; ++i) rp[i] = row_ptr[min(nodeq + i, N)];

    u32 pl[4]; us16 xr[4];
    #pragma unroll
    for (int q = 0; q < 4; ++q) {             // 8 independent loads in flight
        int cnt = rp[q + 1] - rp[q];
        pl[q] = (lane < cnt) ? md[rp[q] + lane] : 0;
        xr[q] = (nodeq + q < N) ? x_in[(nodeq + q) * HID + lane] : (us16)0;
    }

    // ---- phase 1: aggregate, node-serial per wave ----
    #pragma unroll
    for (int q = 0; q < 4; ++q) {
        int node = nodeq + q;
        if (node >= N) break;
        int start = rp[q], cnt = rp[q + 1] - start;
        us16* Hrow = H + (wave * 4 + q) * LSTR;
        Hrow[NREL * HID + lane] = xr[q];      // root/x columns

        float acc = 0.f;
        int runlen = 0, prev = -1;
        u32 mask = 0;

        proc_window(pl[q], min(cnt, 64), x_in, Hrow, lane, acc, runlen, prev, mask);
        for (int w0 = 64; w0 < cnt; w0 += 64) {            // rare overflow windows
            int wcnt = min(64, cnt - w0);
            u32 p2 = (lane < wcnt) ? md[start + w0 + lane] : 0;
            proc_window(p2, wcnt, x_in, Hrow, lane, acc, runlen, prev, mask);
        }
        if (prev >= 0) {
            Hrow[(prev << 6) + lane] = f2b(acc * __builtin_amdgcn_rcpf((float)runlen));
            mask |= 1u << prev;
        }
        #pragma unroll
        for (int r = 0; r < NREL; ++r)
            if (!(mask & (1u << r))) Hrow[(r << 6) + lane] = 0;
    }
    __syncthreads();

    // ---- phase 2: [H|x] @ Wcat ----
    const int n16 = lane & 15, quad = lane >> 4;
    f32x4 acc = {0.f, 0.f, 0.f, 0.f};
    const us16* Abase = H + n16 * LSTR + quad * 8;                            // A[m][k]
    const us16* Bbase = WcatT + (size_t)(wave * 16 + n16) * KD + quad * 8;    // B[k][n]^T
    #pragma unroll 2
    for (int ks = 0; ks < KD / 32; ++ks) {
        bf16x8 af = *(const bf16x8*)(Abase + ks * 32);
        bf16x8 bf = *(const bf16x8*)(Bbase + ks * 32);
        acc = __builtin_amdgcn_mfma_f32_16x16x32_bf16(af, bf, acc, 0, 0, 0);
    }

    int col = wave * 16 + n16;
    float bv = bias[col];
    #pragma unroll
    for (int ri = 0; ri < 4; ++ri) {
        int nl = quad * 4 + ri, node = node0 + nl;   // C/D: col=lane&15, row=quad*4+ri
        if (node < N) {
            float v = acc[ri] + bv;
            if (flags & 1) v = fmaxf(v, 0.f);
            if (flags & 2) out_f32[node * HID + col] = v;
            else           x_out [node * HID + col] = f2b(v);
        }
    }
}

// ---------- host ----------

extern "C" void kernel_launch(void* const* d_in, const int* in_sizes, int n_in,
                              void* d_out, int out_size, void* d_ws, size_t ws_size,
                              hipStream_t stream) {
    const int*   edge_index = (const int*)  d_in[0];
    const int*   edge_type  = (const int*)  d_in[1];
    const float* node_emb   = (const float*)d_in[2];
    const float* W          = (const float*)d_in[3];
    const float* Wroot      = (const float*)d_in[4];
    const float* bias       = (const float*)d_in[5];
    float* out = (float*)d_out;

    const int E = in_sizes[1];
    const int N = in_sizes[2] / HID;
    const int L = in_sizes[5] / HID;
    const int NR16 = N * NREL;

    char* p = (char*)d_ws;
    size_t off = 0;
    auto carve = [&](size_t bytes) {
        void* q = p + off;
        off = (off + bytes + 255) & ~(size_t)255;
        return q;
    };
    int*   counts16 = (int*)  carve((size_t)NR16 * 4);
    int*   segcur   = (int*)  carve((size_t)NR16 * 4);
    int*   row_ptr  = (int*)  carve((size_t)(N + 1) * 4);
    int*   sums     = (int*)  carve(512 * 4);
    u32*   md       = (u32*)  carve((size_t)E * 4);
    us16*  xb0      = (us16*) carve((size_t)N * HID * 2);
    us16*  xb1      = (us16*) carve((size_t)N * HID * 2);
    us16*  WcatT    = (us16*) carve((size_t)L * HID * KD * 2);
    (void)ws_size; (void)n_in; (void)out_size;

    hipMemsetAsync(counts16, 0, (size_t)NR16 * 4, stream);

    int ge  = (E + 255) / 256;
    int nb4 = (NR16 + 4095) / 4096;
    count_kernel<<<ge, 256, 0, stream>>>(edge_index, edge_type, counts16, E);
    scan1<<<nb4, 1024, 0, stream>>>(counts16, segcur, sums, NR16);
    scan2<<<1, 512, 0, stream>>>(sums, nb4, row_ptr, N, E);
    scan3<<<nb4, 1024, 0, stream>>>(segcur, sums, row_ptr, NR16);
    place_kernel<<<ge, 256, 0, stream>>>(edge_index, edge_type, segcur, md, E);
    convx_kernel<<<(N * HID / 4 + 255) / 256, 256, 0, stream>>>(node_emb, xb0, N * HID / 4);
    int wtot = L * HID * KD;
    convw_kernel<<<(wtot + 255) / 256, 256, 0, stream>>>(W, Wroot, WcatT, wtot, L);

    int gl = (N + NPB - 1) / NPB;
    us16* xin = xb0;
    us16* xother = xb1;
    for (int l = 0; l < L; ++l) {
        int last = (l == L - 1);
        int flags = (last ? 2 : 1);
        layer_kernel<<<gl, 256, 0, stream>>>(
            xin, row_ptr, md,
            WcatT + (size_t)l * HID * KD, bias + (size_t)l * HID,
            last ? nullptr : xother, last ? out : nullptr,
            flags, N);
        us16* t = xin; xin = xother; xother = t;
    }
}

// Round 7
// 767.798 us; speedup vs baseline: 2.8178x; 1.0500x over previous
//
#include <hip/hip_runtime.h>

// RGCN, 3 layers. N=100000, E=1.6M, R=16, HID=64.
// Edges counting-sorted by (dst,rel); md = src | rel<<20 (one u32/edge).
// Per layer (16 nodes/block, 4 waves, 4 nodes/wave): phase 1 aggregates
// per-(node,rel) means via run-length fp32 register accumulation; edge
// metadata is scalarized (readlane -> SGPR) so run detection is SALU and
// gathers use saddr form; bf16 flush to LDS H[16][1088].
// Phase 2: out = [H|x] @ Wcat via mfma_f32_16x16x32_bf16 (K=1088).

#define HID   64
#define NREL  16
#define KD    1088          // NREL*HID + HID (root x appended as extra K)
#define NPB   16            // nodes per block (= MFMA M)
#define LSTR  1096          // LDS row stride (pad 1088 -> 1096)

typedef __attribute__((ext_vector_type(8))) short bf16x8;
typedef __attribute__((ext_vector_type(4))) float f32x4;
typedef unsigned short us16;
typedef unsigned int u32;

__device__ __forceinline__ float b2f(us16 u) {
    union { u32 i; float f; } c; c.i = ((u32)u) << 16; return c.f;
}
__device__ __forceinline__ us16 f2b(float f) {   // round-to-nearest-even
    union { float f; u32 i; } c; c.f = f;
    u32 x = c.i;
    return (us16)((x + 0x7FFFu + ((x >> 16) & 1u)) >> 16);
}

// ---------- setup: counting sort by (dst*16+rel) ----------

__global__ void count_kernel(const int* __restrict__ ei, const int* __restrict__ et,
                             int* __restrict__ counts16, int E) {
    int e = blockIdx.x * 256 + threadIdx.x;
    if (e < E) {
        int dst = ei[E + e];
        int t   = et[e];
        atomicAdd(&counts16[dst * NREL + t], 1);
    }
}

__global__ __launch_bounds__(1024) void scan1(const int* __restrict__ counts16,
                                              int* __restrict__ seg,
                                              int* __restrict__ sums, int nr16) {
    __shared__ int s[1024];
    int t = threadIdx.x;
    int g4 = (blockIdx.x * 1024 + t) * 4;
    int c0 = 0, c1 = 0, c2 = 0, c3 = 0;
    if (g4 + 3 < nr16) {
        const int4 v = *(const int4*)(counts16 + g4);
        c0 = v.x; c1 = v.y; c2 = v.z; c3 = v.w;
    } else {
        if (g4 + 0 < nr16) c0 = counts16[g4 + 0];
        if (g4 + 1 < nr16) c1 = counts16[g4 + 1];
        if (g4 + 2 < nr16) c2 = counts16[g4 + 2];
        if (g4 + 3 < nr16) c3 = counts16[g4 + 3];
    }
    int loc = c0 + c1 + c2 + c3;
    s[t] = loc; __syncthreads();
    for (int off = 1; off < 1024; off <<= 1) {
        int tv = (t >= off) ? s[t - off] : 0;
        __syncthreads();
        s[t] += tv;
        __syncthreads();
    }
    int ex = s[t] - loc;
    if (g4 + 0 < nr16) seg[g4 + 0] = ex;
    if (g4 + 1 < nr16) seg[g4 + 1] = ex + c0;
    if (g4 + 2 < nr16) seg[g4 + 2] = ex + c0 + c1;
    if (g4 + 3 < nr16) seg[g4 + 3] = ex + c0 + c1 + c2;
    if (t == 1023) sums[blockIdx.x] = s[1023];
}

__global__ void scan2(int* __restrict__ sums, int nb,
                      int* __restrict__ row_ptr, int N, int E) {  // 1 block, 512 thr
    __shared__ int s[512];
    int t = threadIdx.x;
    int v = (t < nb) ? sums[t] : 0;
    s[t] = v; __syncthreads();
    for (int off = 1; off < 512; off <<= 1) {
        int tv = (t >= off) ? s[t - off] : 0;
        __syncthreads();
        s[t] += tv;
        __syncthreads();
    }
    if (t < nb) sums[t] = s[t] - v;
    if (t == 0) row_ptr[N] = E;
}

__global__ __launch_bounds__(1024) void scan3(int* __restrict__ seg,
                                              const int* __restrict__ sums,
                                              int* __restrict__ row_ptr, int nr16) {
    int t = threadIdx.x;
    int g4 = (blockIdx.x * 1024 + t) * 4;
    int add = sums[blockIdx.x];
    #pragma unroll
    for (int j = 0; j < 4; ++j) {
        int g = g4 + j;
        if (g < nr16) {
            int v = seg[g] + add;
            seg[g] = v;                          // becomes cursor
            if ((g & 15) == 0) row_ptr[g >> 4] = v;
        }
    }
}

// md[pos] = src | rel<<20
__global__ void place_kernel(const int* __restrict__ ei, const int* __restrict__ et,
                             int* __restrict__ cursor16,
                             u32* __restrict__ md, int E) {
    int e = blockIdx.x * 256 + threadIdx.x;
    if (e < E) {
        int src = ei[e], dst = ei[E + e], t = et[e];
        int pos = atomicAdd(&cursor16[dst * NREL + t], 1);
        md[pos] = (u32)src | ((u32)t << 20);
    }
}

__global__ void convx_kernel(const float* __restrict__ x, us16* __restrict__ xb, int n4) {
    int i = blockIdx.x * 256 + threadIdx.x;    // n4 = N*HID/4
    if (i < n4) {
        float4 v = ((const float4*)x)[i];
        us16* o = xb + i * 4;
        o[0] = f2b(v.x); o[1] = f2b(v.y); o[2] = f2b(v.z); o[3] = f2b(v.w);
    }
}

// WcatT[l][h][k], k = r*64+d for k<1024, else root d = k-1024.  bf16.
__global__ void convw_kernel(const float* __restrict__ W, const float* __restrict__ Wroot,
                             us16* __restrict__ WcatT, int total, int L) {
    int i = blockIdx.x * 256 + threadIdx.x;    // total = L*HID*KD
    if (i < total) {
        int l = i / (HID * KD);
        int rem = i % (HID * KD);
        int h = rem / KD, k = rem % KD;
        float v;
        if (k < NREL * HID) {
            int r = k >> 6, d = k & 63;
            v = W[(((size_t)l * NREL + r) * HID + d) * HID + h];
        } else {
            int d = k - NREL * HID;
            v = Wroot[((size_t)l * HID + d) * HID + h];
        }
        WcatT[i] = f2b(v);
    }
}

// ---------- fused layer kernel ----------

// process one 64-edge metadata window held in register p_l.
// prev/runlen/mask and all md-derived values are wave-uniform scalars.
__device__ __forceinline__ void proc_window(
        u32 p_l, int wcnt, const us16* __restrict__ x_in, us16* Hrow, int lane,
        float& acc, int& runlen, int& prev, u32& mask)
{
    #pragma unroll 1
    for (int c = 0; c < wcnt; c += 16) {
        us16 hv[16]; int pe[16];
        #pragma unroll
        for (int j = 0; j < 16; ++j) {           // 16 independent saddr gathers
            int idx = c + j; if (idx >= wcnt) idx = wcnt - 1;
            pe[j] = __builtin_amdgcn_readlane((int)p_l, idx);        // -> SGPR
            hv[j] = x_in[((u32)pe[j] & 0xFFFFFu) * HID + lane];
        }
        int m = wcnt - c; if (m > 16) m = 16;
        #pragma unroll
        for (int j = 0; j < 16; ++j) {
            if (j < m) {                          // scalar bound
                int r = (int)(((u32)pe[j]) >> 20);                   // SALU
                if (r != prev) {                  // s_cmp + s_cbranch
                    if (prev >= 0) {
                        Hrow[(prev << 6) + lane] =
                            f2b(acc * __builtin_amdgcn_rcpf((float)runlen));
                        mask |= 1u << prev;
                    }
                    prev = r; acc = 0.f; runlen = 0;
                }
                acc += b2f(hv[j]); ++runlen;
            }
        }
    }
}

__global__ __launch_bounds__(256, 4) void layer_kernel(
        const us16* __restrict__ x_in,        // bf16 [N,64]
        const int*  __restrict__ row_ptr,     // [N+1]
        const u32*  __restrict__ md,          // sorted by (dst,rel): src | rel<<20
        const us16* __restrict__ WcatT,       // bf16 [64][1088] this layer
        const float* __restrict__ bias,       // fp32 [64] this layer
        us16* __restrict__ x_out,             // bf16 [N,64]  (if !last)
        float* __restrict__ out_f32,          // fp32 [N,64]  (if last)
        int flags, int N)                     // flags: 1=relu, 2=last
{
    __shared__ us16 H[NPB * LSTR];            // 35072 B -> 4 blocks/CU
    const int tid = threadIdx.x, wave = tid >> 6, lane = tid & 63;
    const int node0 = blockIdx.x * NPB;
    const int nodeq = node0 + wave * 4;

    // ---- phase 1 prologue: prefetch 4 nodes' metadata windows + root-x rows ----
    int rp[5];
    #pragma unroll
    for (int i = 0; i < 5; ++i)
        rp[i] = __builtin_amdgcn_readfirstlane(row_ptr[min(nodeq + i, N)]);

    u32 pl[4]; us16 xr[4];
    #pragma unroll
    for (int q = 0; q < 4; ++q) {             // 8 independent loads in flight
        int cnt = rp[q + 1] - rp[q];
        pl[q] = (lane < cnt) ? md[rp[q] + lane] : 0;
        xr[q] = (nodeq + q < N) ? x_in[(nodeq + q) * HID + lane] : (us16)0;
    }

    // ---- phase 1: aggregate, node-serial per wave ----
    #pragma unroll
    for (int q = 0; q < 4; ++q) {
        int node = nodeq + q;
        if (node >= N) break;
        int start = rp[q], cnt = rp[q + 1] - start;
        us16* Hrow = H + (wave * 4 + q) * LSTR;
        Hrow[NREL * HID + lane] = xr[q];      // root/x columns

        float acc = 0.f;
        int runlen = 0, prev = -1;
        u32 mask = 0;

        proc_window(pl[q], min(cnt, 64), x_in, Hrow, lane, acc, runlen, prev, mask);
        for (int w0 = 64; w0 < cnt; w0 += 64) {            // rare overflow windows
            int wcnt = min(64, cnt - w0);
            u32 p2 = (lane < wcnt) ? md[start + w0 + lane] : 0;
            proc_window(p2, wcnt, x_in, Hrow, lane, acc, runlen, prev, mask);
        }
        if (prev >= 0) {
            Hrow[(prev << 6) + lane] = f2b(acc * __builtin_amdgcn_rcpf((float)runlen));
            mask |= 1u << prev;
        }
        #pragma unroll
        for (int r = 0; r < NREL; ++r)
            if (!(mask & (1u << r))) Hrow[(r << 6) + lane] = 0;
    }
    __syncthreads();

    // ---- phase 2: [H|x] @ Wcat ----
    const int n16 = lane & 15, quad = lane >> 4;
    f32x4 acc = {0.f, 0.f, 0.f, 0.f};
    const us16* Abase = H + n16 * LSTR + quad * 8;                            // A[m][k]
    const us16* Bbase = WcatT + (size_t)(wave * 16 + n16) * KD + quad * 8;    // B[k][n]^T
    #pragma unroll 2
    for (int ks = 0; ks < KD / 32; ++ks) {
        bf16x8 af = *(const bf16x8*)(Abase + ks * 32);
        bf16x8 bf = *(const bf16x8*)(Bbase + ks * 32);
        acc = __builtin_amdgcn_mfma_f32_16x16x32_bf16(af, bf, acc, 0, 0, 0);
    }

    int col = wave * 16 + n16;
    float bv = bias[col];
    #pragma unroll
    for (int ri = 0; ri < 4; ++ri) {
        int nl = quad * 4 + ri, node = node0 + nl;   // C/D: col=lane&15, row=quad*4+ri
        if (node < N) {
            float v = acc[ri] + bv;
            if (flags & 1) v = fmaxf(v, 0.f);
            if (flags & 2) out_f32[node * HID + col] = v;
            else           x_out [node * HID + col] = f2b(v);
        }
    }
}

// ---------- host ----------

extern "C" void kernel_launch(void* const* d_in, const int* in_sizes, int n_in,
                              void* d_out, int out_size, void* d_ws, size_t ws_size,
                              hipStream_t stream) {
    const int*   edge_index = (const int*)  d_in[0];
    const int*   edge_type  = (const int*)  d_in[1];
    const float* node_emb   = (const float*)d_in[2];
    const float* W          = (const float*)d_in[3];
    const float* Wroot      = (const float*)d_in[4];
    const float* bias       = (const float*)d_in[5];
    float* out = (float*)d_out;

    const int E = in_sizes[1];
    const int N = in_sizes[2] / HID;
    const int L = in_sizes[5] / HID;
    const int NR16 = N * NREL;

    char* p = (char*)d_ws;
    size_t off = 0;
    auto carve = [&](size_t bytes) {
        void* q = p + off;
        off = (off + bytes + 255) & ~(size_t)255;
        return q;
    };
    int*   counts16 = (int*)  carve((size_t)NR16 * 4);
    int*   segcur   = (int*)  carve((size_t)NR16 * 4);
    int*   row_ptr  = (int*)  carve((size_t)(N + 1) * 4);
    int*   sums     = (int*)  carve(512 * 4);
    u32*   md       = (u32*)  carve((size_t)E * 4);
    us16*  xb0      = (us16*) carve((size_t)N * HID * 2);
    us16*  xb1      = (us16*) carve((size_t)N * HID * 2);
    us16*  WcatT    = (us16*) carve((size_t)L * HID * KD * 2);
    (void)ws_size; (void)n_in; (void)out_size;

    hipMemsetAsync(counts16, 0, (size_t)NR16 * 4, stream);

    int ge  = (E + 255) / 256;
    int nb4 = (NR16 + 4095) / 4096;
    count_kernel<<<ge, 256, 0, stream>>>(edge_index, edge_type, counts16, E);
    scan1<<<nb4, 1024, 0, stream>>>(counts16, segcur, sums, NR16);
    scan2<<<1, 512, 0, stream>>>(sums, nb4, row_ptr, N, E);
    scan3<<<nb4, 1024, 0, stream>>>(segcur, sums, row_ptr, NR16);
    place_kernel<<<ge, 256, 0, stream>>>(edge_index, edge_type, segcur, md, E);
    convx_kernel<<<(N * HID / 4 + 255) / 256, 256, 0, stream>>>(node_emb, xb0, N * HID / 4);
    int wtot = L * HID * KD;
    convw_kernel<<<(wtot + 255) / 256, 256, 0, stream>>>(W, Wroot, WcatT, wtot, L);

    int gl = (N + NPB - 1) / NPB;
    us16* xin = xb0;
    us16* xother = xb1;
    for (int l = 0; l < L; ++l) {
        int last = (l == L - 1);
        int flags = (last ? 2 : 1);
        layer_kernel<<<gl, 256, 0, stream>>>(
            xin, row_ptr, md,
            WcatT + (size_t)l * HID * KD, bias + (size_t)l * HID,
            last ? nullptr : xother, last ? out : nullptr,
            flags, N);
        us16* t = xin; xin = xother; xother = t;
    }
}

// Round 8
// 762.555 us; speedup vs baseline: 2.8372x; 1.0069x over previous
//
#include <hip/hip_runtime.h>

// RGCN, 3 layers. N=100000, E=1.6M, R=16, HID=64.
// Edges counting-sorted by (dst,rel); md = src | rel<<20 (one u32/edge).
// Per layer (16 nodes/block, 4 waves, 4 nodes/wave): phase 1 aggregates
// per-(node,rel) means via run-length fp32 register accumulation; metadata
// scalarized (readlane -> SGPR, run detection in SALU); the first <=16
// edge-row gathers of ALL 4 nodes are issued up front (<=64 loads in
// flight/wave) before any consumption; bf16 flush to LDS H[16][1088].
// Phase 2: out = [H|x] @ Wcat via mfma_f32_16x16x32_bf16 (K=1088).

#define HID   64
#define NREL  16
#define KD    1088          // NREL*HID + HID (root x appended as extra K)
#define NPB   16            // nodes per block (= MFMA M)
#define LSTR  1096          // LDS row stride (pad 1088 -> 1096)

typedef __attribute__((ext_vector_type(8))) short bf16x8;
typedef __attribute__((ext_vector_type(4))) float f32x4;
typedef unsigned short us16;
typedef unsigned int u32;

__device__ __forceinline__ float b2f(us16 u) {
    union { u32 i; float f; } c; c.i = ((u32)u) << 16; return c.f;
}
__device__ __forceinline__ us16 f2b(float f) {   // round-to-nearest-even
    union { float f; u32 i; } c; c.f = f;
    u32 x = c.i;
    return (us16)((x + 0x7FFFu + ((x >> 16) & 1u)) >> 16);
}

// ---------- setup: counting sort by (dst*16+rel) ----------

__global__ void count_kernel(const int* __restrict__ ei, const int* __restrict__ et,
                             int* __restrict__ counts16, int E) {
    int e4 = (blockIdx.x * 256 + threadIdx.x) * 4;
    if (e4 + 3 < E) {
        int4 d = *(const int4*)(ei + E + e4);
        int4 t = *(const int4*)(et + e4);
        atomicAdd(&counts16[d.x * NREL + t.x], 1);
        atomicAdd(&counts16[d.y * NREL + t.y], 1);
        atomicAdd(&counts16[d.z * NREL + t.z], 1);
        atomicAdd(&counts16[d.w * NREL + t.w], 1);
    } else {
        for (int e = e4; e < E; ++e)
            atomicAdd(&counts16[ei[E + e] * NREL + et[e]], 1);
    }
}

__global__ __launch_bounds__(1024) void scan1(const int* __restrict__ counts16,
                                              int* __restrict__ seg,
                                              int* __restrict__ sums, int nr16) {
    __shared__ int s[1024];
    int t = threadIdx.x;
    int g4 = (blockIdx.x * 1024 + t) * 4;
    int c0 = 0, c1 = 0, c2 = 0, c3 = 0;
    if (g4 + 3 < nr16) {
        const int4 v = *(const int4*)(counts16 + g4);
        c0 = v.x; c1 = v.y; c2 = v.z; c3 = v.w;
    } else {
        if (g4 + 0 < nr16) c0 = counts16[g4 + 0];
        if (g4 + 1 < nr16) c1 = counts16[g4 + 1];
        if (g4 + 2 < nr16) c2 = counts16[g4 + 2];
        if (g4 + 3 < nr16) c3 = counts16[g4 + 3];
    }
    int loc = c0 + c1 + c2 + c3;
    s[t] = loc; __syncthreads();
    for (int off = 1; off < 1024; off <<= 1) {
        int tv = (t >= off) ? s[t - off] : 0;
        __syncthreads();
        s[t] += tv;
        __syncthreads();
    }
    int ex = s[t] - loc;
    if (g4 + 0 < nr16) seg[g4 + 0] = ex;
    if (g4 + 1 < nr16) seg[g4 + 1] = ex + c0;
    if (g4 + 2 < nr16) seg[g4 + 2] = ex + c0 + c1;
    if (g4 + 3 < nr16) seg[g4 + 3] = ex + c0 + c1 + c2;
    if (t == 1023) sums[blockIdx.x] = s[1023];
}

__global__ void scan2(int* __restrict__ sums, int nb,
                      int* __restrict__ row_ptr, int N, int E) {  // 1 block, 512 thr
    __shared__ int s[512];
    int t = threadIdx.x;
    int v = (t < nb) ? sums[t] : 0;
    s[t] = v; __syncthreads();
    for (int off = 1; off < 512; off <<= 1) {
        int tv = (t >= off) ? s[t - off] : 0;
        __syncthreads();
        s[t] += tv;
        __syncthreads();
    }
    if (t < nb) sums[t] = s[t] - v;
    if (t == 0) row_ptr[N] = E;
}

__global__ __launch_bounds__(1024) void scan3(int* __restrict__ seg,
                                              const int* __restrict__ sums,
                                              int* __restrict__ row_ptr, int nr16) {
    int t = threadIdx.x;
    int g4 = (blockIdx.x * 1024 + t) * 4;
    int add = sums[blockIdx.x];
    #pragma unroll
    for (int j = 0; j < 4; ++j) {
        int g = g4 + j;
        if (g < nr16) {
            int v = seg[g] + add;
            seg[g] = v;                          // becomes cursor
            if ((g & 15) == 0) row_ptr[g >> 4] = v;
        }
    }
}

// md[pos] = src | rel<<20
__global__ void place_kernel(const int* __restrict__ ei, const int* __restrict__ et,
                             int* __restrict__ cursor16,
                             u32* __restrict__ md, int E) {
    int e4 = (blockIdx.x * 256 + threadIdx.x) * 4;
    if (e4 + 3 < E) {
        int4 sv = *(const int4*)(ei + e4);
        int4 dv = *(const int4*)(ei + E + e4);
        int4 tv = *(const int4*)(et + e4);
        int p0 = atomicAdd(&cursor16[dv.x * NREL + tv.x], 1);
        int p1 = atomicAdd(&cursor16[dv.y * NREL + tv.y], 1);
        int p2 = atomicAdd(&cursor16[dv.z * NREL + tv.z], 1);
        int p3 = atomicAdd(&cursor16[dv.w * NREL + tv.w], 1);
        md[p0] = (u32)sv.x | ((u32)tv.x << 20);
        md[p1] = (u32)sv.y | ((u32)tv.y << 20);
        md[p2] = (u32)sv.z | ((u32)tv.z << 20);
        md[p3] = (u32)sv.w | ((u32)tv.w << 20);
    } else {
        for (int e = e4; e < E; ++e) {
            int pos = atomicAdd(&cursor16[ei[E + e] * NREL + et[e]], 1);
            md[pos] = (u32)ei[e] | ((u32)et[e] << 20);
        }
    }
}

__global__ void convx_kernel(const float* __restrict__ x, us16* __restrict__ xb, int n4) {
    int i = blockIdx.x * 256 + threadIdx.x;    // n4 = N*HID/4
    if (i < n4) {
        float4 v = ((const float4*)x)[i];
        us16* o = xb + i * 4;
        o[0] = f2b(v.x); o[1] = f2b(v.y); o[2] = f2b(v.z); o[3] = f2b(v.w);
    }
}

// WcatT[l][h][k], k = r*64+d for k<1024, else root d = k-1024.  bf16.
__global__ void convw_kernel(const float* __restrict__ W, const float* __restrict__ Wroot,
                             us16* __restrict__ WcatT, int total, int L) {
    int i = blockIdx.x * 256 + threadIdx.x;    // total = L*HID*KD
    if (i < total) {
        int l = i / (HID * KD);
        int rem = i % (HID * KD);
        int h = rem / KD, k = rem % KD;
        float v;
        if (k < NREL * HID) {
            int r = k >> 6, d = k & 63;
            v = W[(((size_t)l * NREL + r) * HID + d) * HID + h];
        } else {
            int d = k - NREL * HID;
            v = Wroot[((size_t)l * HID + d) * HID + h];
        }
        WcatT[i] = f2b(v);
    }
}

// ---------- fused layer kernel ----------

// consume edges [c0, wcnt) of a 64-edge metadata window held in p_l
__device__ __forceinline__ void proc_window(
        u32 p_l, int c0, int wcnt, const us16* __restrict__ x_in, us16* Hrow, int lane,
        float& acc, int& runlen, int& prev, u32& mask)
{
    #pragma unroll 1
    for (int c = c0; c < wcnt; c += 16) {
        us16 hv[16]; int pe[16];
        #pragma unroll
        for (int j = 0; j < 16; ++j) {           // 16 independent saddr gathers
            int idx = c + j; if (idx >= wcnt) idx = wcnt - 1;
            pe[j] = __builtin_amdgcn_readlane((int)p_l, idx);        // -> SGPR
            hv[j] = x_in[((u32)pe[j] & 0xFFFFFu) * HID + lane];
        }
        int m = wcnt - c; if (m > 16) m = 16;
        #pragma unroll
        for (int j = 0; j < 16; ++j) {
            if (j < m) {                          // scalar bound
                int r = (int)(((u32)pe[j]) >> 20);                   // SALU
                if (r != prev) {                  // s_cmp + s_cbranch
                    if (prev >= 0) {
                        Hrow[(prev << 6) + lane] =
                            f2b(acc * __builtin_amdgcn_rcpf((float)runlen));
                        mask |= 1u << prev;
                    }
                    prev = r; acc = 0.f; runlen = 0;
                }
                acc += b2f(hv[j]); ++runlen;
            }
        }
    }
}

__global__ __launch_bounds__(256, 4) void layer_kernel(
        const us16* __restrict__ x_in,        // bf16 [N,64]
        const int*  __restrict__ row_ptr,     // [N+1]
        const u32*  __restrict__ md,          // sorted by (dst,rel): src | rel<<20
        const us16* __restrict__ WcatT,       // bf16 [64][1088] this layer
        const float* __restrict__ bias,       // fp32 [64] this layer
        us16* __restrict__ x_out,             // bf16 [N,64]  (if !last)
        float* __restrict__ out_f32,          // fp32 [N,64]  (if last)
        int flags, int N)                     // flags: 1=relu, 2=last
{
    __shared__ us16 H[NPB * LSTR];            // 35072 B -> 4 blocks/CU
    const int tid = threadIdx.x, wave = tid >> 6, lane = tid & 63;
    const int node0 = blockIdx.x * NPB;
    const int nodeq = node0 + wave * 4;

    // ---- phase 1 prologue: metadata windows + root-x rows, 8 loads in flight ----
    int rp[5];
    #pragma unroll
    for (int i = 0; i < 5; ++i)
        rp[i] = __builtin_amdgcn_readfirstlane(row_ptr[min(nodeq + i, N)]);

    u32 pl[4]; us16 xr[4];
    #pragma unroll
    for (int q = 0; q < 4; ++q) {
        int cnt = rp[q + 1] - rp[q];
        pl[q] = (lane < cnt) ? md[rp[q] + lane] : 0;
        xr[q] = (nodeq + q < N) ? x_in[(nodeq + q) * HID + lane] : (us16)0;
    }

    // ---- deep prefetch: first <=16 edge-rows of ALL 4 nodes (<=64 in flight) ----
    us16 hv[4][16]; int pe[4][16];
    #pragma unroll
    for (int q = 0; q < 4; ++q) {
        int cnt = rp[q + 1] - rp[q];              // uniform
        if (cnt > 0) {
            int w = min(cnt, 16);
            #pragma unroll
            for (int j = 0; j < 16; ++j) {
                int idx = j < w ? j : w - 1;
                pe[q][j] = __builtin_amdgcn_readlane((int)pl[q], idx);   // -> SGPR
                hv[q][j] = x_in[((u32)pe[q][j] & 0xFFFFFu) * HID + lane];
            }
        }
    }

    // ---- phase 1: consume node-serial per wave ----
    #pragma unroll
    for (int q = 0; q < 4; ++q) {
        int node = nodeq + q;
        if (node >= N) break;
        int start = rp[q], cnt = rp[q + 1] - start;
        us16* Hrow = H + (wave * 4 + q) * LSTR;
        Hrow[NREL * HID + lane] = xr[q];      // root/x columns

        float acc = 0.f;
        int runlen = 0, prev = -1;
        u32 mask = 0;

        if (cnt > 0) {
            int m = min(cnt, 16);
            #pragma unroll
            for (int j = 0; j < 16; ++j) {        // consume prefetched batch
                if (j < m) {
                    int r = (int)(((u32)pe[q][j]) >> 20);
                    if (r != prev) {
                        if (prev >= 0) {
                            Hrow[(prev << 6) + lane] =
                                f2b(acc * __builtin_amdgcn_rcpf((float)runlen));
                            mask |= 1u << prev;
                        }
                        prev = r; acc = 0.f; runlen = 0;
                    }
                    acc += b2f(hv[q][j]); ++runlen;
                }
            }
            if (cnt > 16)                          // rest of window 0 (edges 16..63)
                proc_window(pl[q], 16, min(cnt, 64), x_in, Hrow, lane,
                            acc, runlen, prev, mask);
            for (int w0 = 64; w0 < cnt; w0 += 64) {            // rare overflow windows
                int wcnt = min(64, cnt - w0);
                u32 p2 = (lane < wcnt) ? md[start + w0 + lane] : 0;
                proc_window(p2, 0, wcnt, x_in, Hrow, lane, acc, runlen, prev, mask);
            }
        }
        if (prev >= 0) {
            Hrow[(prev << 6) + lane] = f2b(acc * __builtin_amdgcn_rcpf((float)runlen));
            mask |= 1u << prev;
        }
        #pragma unroll
        for (int r = 0; r < NREL; ++r)
            if (!(mask & (1u << r))) Hrow[(r << 6) + lane] = 0;
    }
    __syncthreads();

    // ---- phase 2: [H|x] @ Wcat ----
    const int n16 = lane & 15, quad = lane >> 4;
    f32x4 acc = {0.f, 0.f, 0.f, 0.f};
    const us16* Abase = H + n16 * LSTR + quad * 8;                            // A[m][k]
    const us16* Bbase = WcatT + (size_t)(wave * 16 + n16) * KD + quad * 8;    // B[k][n]^T
    #pragma unroll 2
    for (int ks = 0; ks < KD / 32; ++ks) {
        bf16x8 af = *(const bf16x8*)(Abase + ks * 32);
        bf16x8 bf = *(const bf16x8*)(Bbase + ks * 32);
        acc = __builtin_amdgcn_mfma_f32_16x16x32_bf16(af, bf, acc, 0, 0, 0);
    }

    int col = wave * 16 + n16;
    float bv = bias[col];
    #pragma unroll
    for (int ri = 0; ri < 4; ++ri) {
        int nl = quad * 4 + ri, node = node0 + nl;   // C/D: col=lane&15, row=quad*4+ri
        if (node < N) {
            float v = acc[ri] + bv;
            if (flags & 1) v = fmaxf(v, 0.f);
            if (flags & 2) out_f32[node * HID + col] = v;
            else           x_out [node * HID + col] = f2b(v);
        }
    }
}

// ---------- host ----------

extern "C" void kernel_launch(void* const* d_in, const int* in_sizes, int n_in,
                              void* d_out, int out_size, void* d_ws, size_t ws_size,
                              hipStream_t stream) {
    const int*   edge_index = (const int*)  d_in[0];
    const int*   edge_type  = (const int*)  d_in[1];
    const float* node_emb   = (const float*)d_in[2];
    const float* W          = (const float*)d_in[3];
    const float* Wroot      = (const float*)d_in[4];
    const float* bias       = (const float*)d_in[5];
    float* out = (float*)d_out;

    const int E = in_sizes[1];
    const int N = in_sizes[2] / HID;
    const int L = in_sizes[5] / HID;
    const int NR16 = N * NREL;

    char* p = (char*)d_ws;
    size_t off = 0;
    auto carve = [&](size_t bytes) {
        void* q = p + off;
        off = (off + bytes + 255) & ~(size_t)255;
        return q;
    };
    int*   counts16 = (int*)  carve((size_t)NR16 * 4);
    int*   segcur   = (int*)  carve((size_t)NR16 * 4);
    int*   row_ptr  = (int*)  carve((size_t)(N + 1) * 4);
    int*   sums     = (int*)  carve(512 * 4);
    u32*   md       = (u32*)  carve((size_t)E * 4);
    us16*  xb0      = (us16*) carve((size_t)N * HID * 2);
    us16*  xb1      = (us16*) carve((size_t)N * HID * 2);
    us16*  WcatT    = (us16*) carve((size_t)L * HID * KD * 2);
    (void)ws_size; (void)n_in; (void)out_size;

    hipMemsetAsync(counts16, 0, (size_t)NR16 * 4, stream);

    int ge4 = (E / 4 + 255) / 256;
    int nb4 = (NR16 + 4095) / 4096;
    count_kernel<<<ge4, 256, 0, stream>>>(edge_index, edge_type, counts16, E);
    scan1<<<nb4, 1024, 0, stream>>>(counts16, segcur, sums, NR16);
    scan2<<<1, 512, 0, stream>>>(sums, nb4, row_ptr, N, E);
    scan3<<<nb4, 1024, 0, stream>>>(segcur, sums, row_ptr, NR16);
    place_kernel<<<ge4, 256, 0, stream>>>(edge_index, edge_type, segcur, md, E);
    convx_kernel<<<(N * HID / 4 + 255) / 256, 256, 0, stream>>>(node_emb, xb0, N * HID / 4);
    int wtot = L * HID * KD;
    convw_kernel<<<(wtot + 255) / 256, 256, 0, stream>>>(W, Wroot, WcatT, wtot, L);

    int gl = (N + NPB - 1) / NPB;
    us16* xin = xb0;
    us16* xother = xb1;
    for (int l = 0; l < L; ++l) {
        int last = (l == L - 1);
        int flags = (last ? 2 : 1);
        layer_kernel<<<gl, 256, 0, stream>>>(
            xin, row_ptr, md,
            WcatT + (size_t)l * HID * KD, bias + (size_t)l * HID,
            last ? nullptr : xother, last ? out : nullptr,
            flags, N);
        us16* t = xin; xin = xother; xother = t;
    }
}

// Round 9
// 693.615 us; speedup vs baseline: 3.1191x; 1.0994x over previous
//
#include <hip/hip_runtime.h>

// RGCN, 3 layers. N=100000, E=1.6M, R=16, HID=64.
// Edges counting-sorted by (dst,rel); md = src | rel<<20 (one u32/edge).
// Per layer: 512-thread blocks (8 waves), 16 nodes/block, 2 nodes/wave.
// Phase 1: run-length fp32 register accumulation per (node,rel) segment,
// metadata scalarized (readlane -> SGPR, SALU run detection), 16-deep
// gather batches; 32 waves/CU for gather-latency hiding. bf16 flush to
// LDS H[16][1088]. Phase 2 (waves 0-3 only): out = [H|x] @ Wcat via
// mfma_f32_16x16x32_bf16 (K=1088).

#define HID   64
#define NREL  16
#define KD    1088          // NREL*HID + HID (root x appended as extra K)
#define NPB   16            // nodes per block (= MFMA M)
#define NPW   2             // nodes per wave (8 waves)
#define LSTR  1096          // LDS row stride (pad 1088 -> 1096)

typedef __attribute__((ext_vector_type(8))) short bf16x8;
typedef __attribute__((ext_vector_type(4))) float f32x4;
typedef unsigned short us16;
typedef unsigned int u32;

__device__ __forceinline__ float b2f(us16 u) {
    union { u32 i; float f; } c; c.i = ((u32)u) << 16; return c.f;
}
__device__ __forceinline__ us16 f2b(float f) {   // round-to-nearest-even
    union { float f; u32 i; } c; c.f = f;
    u32 x = c.i;
    return (us16)((x + 0x7FFFu + ((x >> 16) & 1u)) >> 16);
}

// ---------- setup: counting sort by (dst*16+rel) ----------

__global__ void count_kernel(const int* __restrict__ ei, const int* __restrict__ et,
                             int* __restrict__ counts16, int E) {
    int e4 = (blockIdx.x * 256 + threadIdx.x) * 4;
    if (e4 + 3 < E) {
        int4 d = *(const int4*)(ei + E + e4);
        int4 t = *(const int4*)(et + e4);
        atomicAdd(&counts16[d.x * NREL + t.x], 1);
        atomicAdd(&counts16[d.y * NREL + t.y], 1);
        atomicAdd(&counts16[d.z * NREL + t.z], 1);
        atomicAdd(&counts16[d.w * NREL + t.w], 1);
    } else {
        for (int e = e4; e < E; ++e)
            atomicAdd(&counts16[ei[E + e] * NREL + et[e]], 1);
    }
}

__global__ __launch_bounds__(1024) void scan1(const int* __restrict__ counts16,
                                              int* __restrict__ seg,
                                              int* __restrict__ sums, int nr16) {
    __shared__ int s[1024];
    int t = threadIdx.x;
    int g4 = (blockIdx.x * 1024 + t) * 4;
    int c0 = 0, c1 = 0, c2 = 0, c3 = 0;
    if (g4 + 3 < nr16) {
        const int4 v = *(const int4*)(counts16 + g4);
        c0 = v.x; c1 = v.y; c2 = v.z; c3 = v.w;
    } else {
        if (g4 + 0 < nr16) c0 = counts16[g4 + 0];
        if (g4 + 1 < nr16) c1 = counts16[g4 + 1];
        if (g4 + 2 < nr16) c2 = counts16[g4 + 2];
        if (g4 + 3 < nr16) c3 = counts16[g4 + 3];
    }
    int loc = c0 + c1 + c2 + c3;
    s[t] = loc; __syncthreads();
    for (int off = 1; off < 1024; off <<= 1) {
        int tv = (t >= off) ? s[t - off] : 0;
        __syncthreads();
        s[t] += tv;
        __syncthreads();
    }
    int ex = s[t] - loc;
    if (g4 + 0 < nr16) seg[g4 + 0] = ex;
    if (g4 + 1 < nr16) seg[g4 + 1] = ex + c0;
    if (g4 + 2 < nr16) seg[g4 + 2] = ex + c0 + c1;
    if (g4 + 3 < nr16) seg[g4 + 3] = ex + c0 + c1 + c2;
    if (t == 1023) sums[blockIdx.x] = s[1023];
}

__global__ void scan2(int* __restrict__ sums, int nb,
                      int* __restrict__ row_ptr, int N, int E) {  // 1 block, 512 thr
    __shared__ int s[512];
    int t = threadIdx.x;
    int v = (t < nb) ? sums[t] : 0;
    s[t] = v; __syncthreads();
    for (int off = 1; off < 512; off <<= 1) {
        int tv = (t >= off) ? s[t - off] : 0;
        __syncthreads();
        s[t] += tv;
        __syncthreads();
    }
    if (t < nb) sums[t] = s[t] - v;
    if (t == 0) row_ptr[N] = E;
}

__global__ __launch_bounds__(1024) void scan3(int* __restrict__ seg,
                                              const int* __restrict__ sums,
                                              int* __restrict__ row_ptr, int nr16) {
    int t = threadIdx.x;
    int g4 = (blockIdx.x * 1024 + t) * 4;
    int add = sums[blockIdx.x];
    #pragma unroll
    for (int j = 0; j < 4; ++j) {
        int g = g4 + j;
        if (g < nr16) {
            int v = seg[g] + add;
            seg[g] = v;                          // becomes cursor
            if ((g & 15) == 0) row_ptr[g >> 4] = v;
        }
    }
}

// md[pos] = src | rel<<20
__global__ void place_kernel(const int* __restrict__ ei, const int* __restrict__ et,
                             int* __restrict__ cursor16,
                             u32* __restrict__ md, int E) {
    int e4 = (blockIdx.x * 256 + threadIdx.x) * 4;
    if (e4 + 3 < E) {
        int4 sv = *(const int4*)(ei + e4);
        int4 dv = *(const int4*)(ei + E + e4);
        int4 tv = *(const int4*)(et + e4);
        int p0 = atomicAdd(&cursor16[dv.x * NREL + tv.x], 1);
        int p1 = atomicAdd(&cursor16[dv.y * NREL + tv.y], 1);
        int p2 = atomicAdd(&cursor16[dv.z * NREL + tv.z], 1);
        int p3 = atomicAdd(&cursor16[dv.w * NREL + tv.w], 1);
        md[p0] = (u32)sv.x | ((u32)tv.x << 20);
        md[p1] = (u32)sv.y | ((u32)tv.y << 20);
        md[p2] = (u32)sv.z | ((u32)tv.z << 20);
        md[p3] = (u32)sv.w | ((u32)tv.w << 20);
    } else {
        for (int e = e4; e < E; ++e) {
            int pos = atomicAdd(&cursor16[ei[E + e] * NREL + et[e]], 1);
            md[pos] = (u32)ei[e] | ((u32)et[e] << 20);
        }
    }
}

__global__ void convx_kernel(const float* __restrict__ x, us16* __restrict__ xb, int n4) {
    int i = blockIdx.x * 256 + threadIdx.x;    // n4 = N*HID/4
    if (i < n4) {
        float4 v = ((const float4*)x)[i];
        us16* o = xb + i * 4;
        o[0] = f2b(v.x); o[1] = f2b(v.y); o[2] = f2b(v.z); o[3] = f2b(v.w);
    }
}

// WcatT[l][h][k], k = r*64+d for k<1024, else root d = k-1024.  bf16.
__global__ void convw_kernel(const float* __restrict__ W, const float* __restrict__ Wroot,
                             us16* __restrict__ WcatT, int total, int L) {
    int i = blockIdx.x * 256 + threadIdx.x;    // total = L*HID*KD
    if (i < total) {
        int l = i / (HID * KD);
        int rem = i % (HID * KD);
        int h = rem / KD, k = rem % KD;
        float v;
        if (k < NREL * HID) {
            int r = k >> 6, d = k & 63;
            v = W[(((size_t)l * NREL + r) * HID + d) * HID + h];
        } else {
            int d = k - NREL * HID;
            v = Wroot[((size_t)l * HID + d) * HID + h];
        }
        WcatT[i] = f2b(v);
    }
}

// ---------- fused layer kernel ----------

// consume edges [c0, wcnt) of a 64-edge metadata window held in p_l
__device__ __forceinline__ void proc_window(
        u32 p_l, int c0, int wcnt, const us16* __restrict__ x_in, us16* Hrow, int lane,
        float& acc, int& runlen, int& prev, u32& mask)
{
    #pragma unroll 1
    for (int c = c0; c < wcnt; c += 16) {
        us16 hv[16]; int pe[16];
        #pragma unroll
        for (int j = 0; j < 16; ++j) {           // 16 independent saddr gathers
            int idx = c + j; if (idx >= wcnt) idx = wcnt - 1;
            pe[j] = __builtin_amdgcn_readlane((int)p_l, idx);        // -> SGPR
            hv[j] = x_in[((u32)pe[j] & 0xFFFFFu) * HID + lane];
        }
        int m = wcnt - c; if (m > 16) m = 16;
        #pragma unroll
        for (int j = 0; j < 16; ++j) {
            if (j < m) {                          // scalar bound
                int r = (int)(((u32)pe[j]) >> 20);                   // SALU
                if (r != prev) {                  // s_cmp + s_cbranch
                    if (prev >= 0) {
                        Hrow[(prev << 6) + lane] =
                            f2b(acc * __builtin_amdgcn_rcpf((float)runlen));
                        mask |= 1u << prev;
                    }
                    prev = r; acc = 0.f; runlen = 0;
                }
                acc += b2f(hv[j]); ++runlen;
            }
        }
    }
}

__global__ __launch_bounds__(512, 8) void layer_kernel(
        const us16* __restrict__ x_in,        // bf16 [N,64]
        const int*  __restrict__ row_ptr,     // [N+1]
        const u32*  __restrict__ md,          // sorted by (dst,rel): src | rel<<20
        const us16* __restrict__ WcatT,       // bf16 [64][1088] this layer
        const float* __restrict__ bias,       // fp32 [64] this layer
        us16* __restrict__ x_out,             // bf16 [N,64]  (if !last)
        float* __restrict__ out_f32,          // fp32 [N,64]  (if last)
        int flags, int N)                     // flags: 1=relu, 2=last
{
    __shared__ us16 H[NPB * LSTR];            // 35072 B -> 4 blocks/CU (32 waves)
    const int tid = threadIdx.x, wave = tid >> 6, lane = tid & 63;
    const int node0 = blockIdx.x * NPB;
    const int nodeq = node0 + wave * NPW;

    // ---- phase 1 prologue: metadata windows + root-x rows in flight ----
    int rp[NPW + 1];
    #pragma unroll
    for (int i = 0; i <= NPW; ++i)
        rp[i] = __builtin_amdgcn_readfirstlane(row_ptr[min(nodeq + i, N)]);

    u32 pl[NPW]; us16 xr[NPW];
    #pragma unroll
    for (int q = 0; q < NPW; ++q) {
        int cnt = rp[q + 1] - rp[q];
        pl[q] = (lane < cnt) ? md[rp[q] + lane] : 0;
        xr[q] = (nodeq + q < N) ? x_in[(nodeq + q) * HID + lane] : (us16)0;
    }

    // ---- phase 1: consume node-serial per wave (2 nodes) ----
    #pragma unroll
    for (int q = 0; q < NPW; ++q) {
        int node = nodeq + q;
        if (node >= N) break;
        int start = rp[q], cnt = rp[q + 1] - start;
        us16* Hrow = H + (wave * NPW + q) * LSTR;
        Hrow[NREL * HID + lane] = xr[q];      // root/x columns

        float acc = 0.f;
        int runlen = 0, prev = -1;
        u32 mask = 0;

        proc_window(pl[q], 0, min(cnt, 64), x_in, Hrow, lane, acc, runlen, prev, mask);
        for (int w0 = 64; w0 < cnt; w0 += 64) {            // rare overflow windows
            int wcnt = min(64, cnt - w0);
            u32 p2 = (lane < wcnt) ? md[start + w0 + lane] : 0;
            proc_window(p2, 0, wcnt, x_in, Hrow, lane, acc, runlen, prev, mask);
        }
        if (prev >= 0) {
            Hrow[(prev << 6) + lane] = f2b(acc * __builtin_amdgcn_rcpf((float)runlen));
            mask |= 1u << prev;
        }
        #pragma unroll
        for (int r = 0; r < NREL; ++r)
            if (!(mask & (1u << r))) Hrow[(r << 6) + lane] = 0;
    }
    __syncthreads();

    // ---- phase 2 (waves 0-3): [H|x] @ Wcat ----
    if (wave < 4) {
        const int n16 = lane & 15, quad = lane >> 4;
        f32x4 acc = {0.f, 0.f, 0.f, 0.f};
        const us16* Abase = H + n16 * LSTR + quad * 8;                         // A[m][k]
        const us16* Bbase = WcatT + (size_t)(wave * 16 + n16) * KD + quad * 8; // B[k][n]^T
        #pragma unroll 2
        for (int ks = 0; ks < KD / 32; ++ks) {
            bf16x8 af = *(const bf16x8*)(Abase + ks * 32);
            bf16x8 bf = *(const bf16x8*)(Bbase + ks * 32);
            acc = __builtin_amdgcn_mfma_f32_16x16x32_bf16(af, bf, acc, 0, 0, 0);
        }

        int col = wave * 16 + n16;
        float bv = bias[col];
        #pragma unroll
        for (int ri = 0; ri < 4; ++ri) {
            int nl = quad * 4 + ri, node = node0 + nl;  // C/D: col=lane&15, row=quad*4+ri
            if (node < N) {
                float v = acc[ri] + bv;
                if (flags & 1) v = fmaxf(v, 0.f);
                if (flags & 2) out_f32[node * HID + col] = v;
                else           x_out [node * HID + col] = f2b(v);
            }
        }
    }
}

// ---------- host ----------

extern "C" void kernel_launch(void* const* d_in, const int* in_sizes, int n_in,
                              void* d_out, int out_size, void* d_ws, size_t ws_size,
                              hipStream_t stream) {
    const int*   edge_index = (const int*)  d_in[0];
    const int*   edge_type  = (const int*)  d_in[1];
    const float* node_emb   = (const float*)d_in[2];
    const float* W          = (const float*)d_in[3];
    const float* Wroot      = (const float*)d_in[4];
    const float* bias       = (const float*)d_in[5];
    float* out = (float*)d_out;

    const int E = in_sizes[1];
    const int N = in_sizes[2] / HID;
    const int L = in_sizes[5] / HID;
    const int NR16 = N * NREL;

    char* p = (char*)d_ws;
    size_t off = 0;
    auto carve = [&](size_t bytes) {
        void* q = p + off;
        off = (off + bytes + 255) & ~(size_t)255;
        return q;
    };
    int*   counts16 = (int*)  carve((size_t)NR16 * 4);
    int*   segcur   = (int*)  carve((size_t)NR16 * 4);
    int*   row_ptr  = (int*)  carve((size_t)(N + 1) * 4);
    int*   sums     = (int*)  carve(512 * 4);
    u32*   md       = (u32*)  carve((size_t)E * 4);
    us16*  xb0      = (us16*) carve((size_t)N * HID * 2);
    us16*  xb1      = (us16*) carve((size_t)N * HID * 2);
    us16*  WcatT    = (us16*) carve((size_t)L * HID * KD * 2);
    (void)ws_size; (void)n_in; (void)out_size;

    hipMemsetAsync(counts16, 0, (size_t)NR16 * 4, stream);

    int ge4 = (E / 4 + 255) / 256;
    int nb4 = (NR16 + 4095) / 4096;
    count_kernel<<<ge4, 256, 0, stream>>>(edge_index, edge_type, counts16, E);
    scan1<<<nb4, 1024, 0, stream>>>(counts16, segcur, sums, NR16);
    scan2<<<1, 512, 0, stream>>>(sums, nb4, row_ptr, N, E);
    scan3<<<nb4, 1024, 0, stream>>>(segcur, sums, row_ptr, NR16);
    place_kernel<<<ge4, 256, 0, stream>>>(edge_index, edge_type, segcur, md, E);
    convx_kernel<<<(N * HID / 4 + 255) / 256, 256, 0, stream>>>(node_emb, xb0, N * HID / 4);
    int wtot = L * HID * KD;
    convw_kernel<<<(wtot + 255) / 256, 256, 0, stream>>>(W, Wroot, WcatT, wtot, L);

    int gl = (N + NPB - 1) / NPB;
    us16* xin = xb0;
    us16* xother = xb1;
    for (int l = 0; l < L; ++l) {
        int last = (l == L - 1);
        int flags = (last ? 2 : 1);
        layer_kernel<<<gl, 512, 0, stream>>>(
            xin, row_ptr, md,
            WcatT + (size_t)l * HID * KD, bias + (size_t)l * HID,
            last ? nullptr : xother, last ? out : nullptr,
            flags, N);
        us16* t = xin; xin = xother; xother = t;
    }
}